// Round 4
// baseline (141.674 us; speedup 1.0000x reference)
//
#include <hip/hip_runtime.h>
#include <hip/hip_bf16.h>

// Dim indices: N=0, K=1, C=2, P=3, Q=4, R=5, S=6
// DIM_MASK rows  -> Input{N,C,P,Q}=0x1D  Weight{K,C,R,S}=0x66  Output{N,K,P,Q}=0x1B
// REUSE_MASK rows-> Input{K}=0x02        Weight{N,P,Q}=0x19    Output{C,R,S}=0x64

typedef const __attribute__((address_space(1))) void* gptr_t;
typedef __attribute__((address_space(3))) void* lptr_t;

#define BLK 128   // 128 threads -> 28.7 KB LDS/block -> ~5 blocks/CU residency

__global__ __launch_bounds__(BLK) void hpm_fused(
    const float* __restrict__ T, const float* __restrict__ S,
    const float* __restrict__ PE, const float* __restrict__ BUF,
    double* __restrict__ part, unsigned* __restrict__ cnt,
    float* __restrict__ out, int G, int NB)
{
    __shared__ float ldsT[BLK * 28];   // 14 KB
    __shared__ float ldsS[BLK * 28];   // 14 KB

    const int tid = threadIdx.x;
    const int wid = tid >> 6;
    const int g0  = blockIdx.x * BLK;
    const int g   = g0 + tid;
    const bool full = (g0 + BLK <= G);   // block-uniform

    float4 tv[7], sv[7];
    bool have = false;

    if (full) {
        const float* gT = T + (size_t)g0 * 28;
        const float* gS = S + (size_t)g0 * 28;
        #pragma unroll
        for (int k = 0; k < 7; ++k) {
            const int fidx = k * BLK + tid;            // per-lane float4 index in chunk
            const int uoff = (k * BLK + wid * 64) * 4; // wave-uniform LDS float offset
            __builtin_amdgcn_global_load_lds((gptr_t)(gT + (size_t)fidx * 4),
                                             (lptr_t)&ldsT[uoff], 16, 0, 0);
            __builtin_amdgcn_global_load_lds((gptr_t)(gS + (size_t)fidx * 4),
                                             (lptr_t)&ldsS[uoff], 16, 0, 0);
        }
        __syncthreads();   // drains vmcnt before barrier

        const float4* Tl = reinterpret_cast<const float4*>(&ldsT[tid * 28]);
        const float4* Sl = reinterpret_cast<const float4*>(&ldsS[tid * 28]);
        #pragma unroll
        for (int d = 0; d < 7; ++d) { tv[d] = Tl[d]; sv[d] = Sl[d]; }
        have = true;
    } else if (g < G) {
        const float4* Tp = reinterpret_cast<const float4*>(T) + (size_t)g * 7;
        const float4* Sp = reinterpret_cast<const float4*>(S) + (size_t)g * 7;
        #pragma unroll
        for (int d = 0; d < 7; ++d) { tv[d] = Tp[d]; sv[d] = Sp[d]; }
        have = true;
    }

    double lat = 0.0, en = 0.0, mis = 0.0;

    if (have) {
        const float pe = PE[0];
        const float sq = sqrtf(pe);
        const float b0 = BUF[0], b1 = BUF[1], b2 = BUF[2];

        float fpI[3] = {1.f,1.f,1.f}, fpW[3] = {1.f,1.f,1.f}, fpO[3] = {1.f,1.f,1.f};
        float otI[3] = {1.f,1.f,1.f}, otW[3] = {1.f,1.f,1.f}, otO[3] = {1.f,1.f,1.f};
        float ruI[3] = {1.f,1.f,1.f}, ruW[3] = {1.f,1.f,1.f}, ruO[3] = {1.f,1.f,1.f};
        float macs = 1.f;

        constexpr unsigned IN_D = 0x1D, WT_D = 0x66, OU_D = 0x1B;
        constexpr unsigned IN_R = 0x02, WT_R = 0x19, OU_R = 0x64;

        #pragma unroll
        for (int d = 0; d < 7; ++d) {
            const float4 t = tv[d];
            const float4 s = sv[d];

            const float ct0 = t.x;
            const float ct1 = ct0 * t.y;
            const float ct2 = ct1 * t.z;
            const float u0 = t.x * s.x, u1 = t.y * s.y, u2 = t.z * s.z, u3 = t.w * s.w;
            const float cs0 = u0;
            const float cs1 = cs0 * u1;
            const float cs2 = cs1 * u2;
            const float cs3 = cs2 * u3;
            const float st3 = t.w;
            const float st2 = t.z * st3;
            const float st1 = t.y * st2;

            macs *= cs3;

            if ((IN_D >> d) & 1) {
                fpI[0] *= cs0; fpI[1] *= cs1; fpI[2] *= cs2;
                otI[0] *= st1; otI[1] *= st2; otI[2] *= st3;
            }
            if ((WT_D >> d) & 1) {
                fpW[0] *= cs0; fpW[1] *= cs1; fpW[2] *= cs2;
                otW[0] *= st1; otW[1] *= st2; otW[2] *= st3;
            }
            if ((OU_D >> d) & 1) {
                fpO[0] *= cs0; fpO[1] *= cs1; fpO[2] *= cs2;
                otO[0] *= st1; otO[1] *= st2; otO[2] *= st3;
            }
            if ((IN_R >> d) & 1) { ruI[0] *= ct0; ruI[1] *= ct1; ruI[2] *= ct2; }
            if ((WT_R >> d) & 1) { ruW[0] *= ct0; ruW[1] *= ct1; ruW[2] *= ct2; }
            if ((OU_R >> d) & 1) { ruO[0] *= ct0; ruO[1] *= ct1; ruO[2] *= ct2; }
        }

        const float acc0 = 4.f * ( fpI[2] * otI[2] / (ruI[2] + 1e-9f)
                                 + fpW[2] * otW[2] / (ruW[2] + 1e-9f)
                                 + fpO[2] * otO[2] / (ruO[2] + 1e-9f) );
        const float acc1 = 4.f * ( fpI[1] * otI[1] / (ruI[1] + 1e-9f)
                                 + fpW[1] * otW[1] / (ruW[1] + 1e-9f)
                                 + fpO[1] * otO[1] / (ruO[1] + 1e-9f) );
        const float acc2 = 4.f * ( fpI[0] * otI[0] / (ruI[0] + 1e-9f)
                                 + fpW[0] * otW[0] / (ruW[0] + 1e-9f)
                                 + fpO[0] * otO[0] / (ruO[0] + 1e-9f) );

        const float bw_dram   = 100.0f * 1e9f + 1e-9f;
        const float bw_onchip = sq * 8e9f + 1e-9f;   // 2*sq*4B*1000MHz in B/s
        const float ml = fmaxf(acc0 / bw_dram,
                               fmaxf(acc1, acc2) / bw_onchip);
        const float cl = macs / (pe * 1e9f + 1e-9f);
        lat = (double)fmaxf(cl, ml);

        const float epa0 = 1.2f  + 0.002f * b2;
        const float epa1 = 0.52f + 0.01f  * (b1 / sq);
        const float epa2 = 0.18f;
        en = (double)(macs * 0.56f + (acc0 * epa0 + acc1 * epa1 + acc2 * epa2) * 0.25f);

        const float c = 4.f / 1024.f;
        const float r0 = (fpI[0] + fpW[0] + fpO[0]) * c;
        const float r1 = (fpI[1] + fpW[1] + fpO[1]) * c;
        const float r2 = (fpI[2] + fpW[2] + fpO[2]) * c;
        const float d0 = fmaxf(r0 - b0, 0.f);
        const float d1 = fmaxf(r1 - b1, 0.f);
        const float d2 = fmaxf(r2 - b2, 0.f);
        mis = (double)d0 * d0 + (double)d1 * d1 + (double)d2 * d2;
    }

    // wave (64-lane) shuffle reduction
    #pragma unroll
    for (int off = 32; off > 0; off >>= 1) {
        lat += __shfl_down(lat, off);
        en  += __shfl_down(en,  off);
        mis += __shfl_down(mis, off);
    }

    __shared__ double sred[3][2];
    const int lane = tid & 63;
    if (lane == 0) { sred[0][wid] = lat; sred[1][wid] = en; sred[2][wid] = mis; }
    __syncthreads();

    __shared__ unsigned sflag;
    if (tid == 0) {
        const double L = sred[0][0] + sred[0][1];
        const double E = sred[1][0] + sred[1][1];
        const double M = sred[2][0] + sred[2][1];
        // private per-block slots, plane-major for coalesced final reads
        part[0 * NB + blockIdx.x] = L;
        part[1 * NB + blockIdx.x] = E;
        part[2 * NB + blockIdx.x] = M;
        __threadfence();                         // release partials (device scope)
        const unsigned old = atomicAdd(cnt, 1u); // device-scope RMW
        sflag = (old == (unsigned)(NB - 1)) ? 1u : 0u;
    }
    __syncthreads();

    if (sflag) {
        __threadfence();   // acquire all partials
        double L = 0.0, E = 0.0, M = 0.0;
        for (int i = tid; i < NB; i += BLK) {
            L += part[0 * NB + i];
            E += part[1 * NB + i];
            M += part[2 * NB + i];
        }
        #pragma unroll
        for (int off = 32; off > 0; off >>= 1) {
            L += __shfl_down(L, off);
            E += __shfl_down(E, off);
            M += __shfl_down(M, off);
        }
        if (lane == 0) { sred[0][wid] = L; sred[1][wid] = E; sred[2][wid] = M; }
        __syncthreads();
        if (tid == 0) {
            out[0] = (float)(sred[0][0] + sred[0][1]);                    // total_latency
            out[1] = (float)(sred[1][0] + sred[1][1]);                    // total_energy
            out[2] = PE[0] * 0.01f + (BUF[0] + BUF[1] + BUF[2]) * 0.005f; // area
            out[3] = (float)(sred[2][0] + sred[2][1]);                    // total_mismatch
        }
    }
}

extern "C" void kernel_launch(void* const* d_in, const int* in_sizes, int n_in,
                              void* d_out, int out_size, void* d_ws, size_t ws_size,
                              hipStream_t stream) {
    const float* T   = (const float*)d_in[0];   // temporal_factors [G,7,4]
    const float* S   = (const float*)d_in[1];   // spatial_factors  [G,7,4]
    const float* PE  = (const float*)d_in[2];   // num_pes [1]
    const float* BUF = (const float*)d_in[3];   // buffer_sizes_kb [3]
    float* out = (float*)d_out;

    const int G  = in_sizes[0] / 28;
    const int NB = (G + BLK - 1) / BLK;

    double*   part = (double*)d_ws;                          // 3 * NB doubles
    unsigned* cnt  = (unsigned*)((char*)d_ws + (size_t)3 * NB * sizeof(double));

    hipMemsetAsync(cnt, 0, sizeof(unsigned), stream);        // graph-capturable
    hipLaunchKernelGGL(hpm_fused, dim3(NB), dim3(BLK), 0, stream,
                       T, S, PE, BUF, part, cnt, out, G, NB);
}

// Round 5
// 28.037 us; speedup vs baseline: 5.0531x; 5.0531x over previous
//
#include <hip/hip_runtime.h>
#include <hip/hip_bf16.h>

// Dim indices: N=0, K=1, C=2, P=3, Q=4, R=5, S=6
// DIM_MASK rows  -> Input{N,C,P,Q}=0x1D  Weight{K,C,R,S}=0x66  Output{N,K,P,Q}=0x1B
// REUSE_MASK rows-> Input{K}=0x02        Weight{N,P,Q}=0x19    Output{C,R,S}=0x64

typedef const __attribute__((address_space(1))) void* gptr_t;
typedef __attribute__((address_space(3))) void* lptr_t;

// 256 threads, ONE 28 KB LDS buffer staged twice (T then S):
// 28.9 KB/block -> ~5 blocks/CU residency (vs 57.8 KB -> 1-2 blocks).
__global__ __launch_bounds__(256) void hpm_main(
    const float* __restrict__ T, const float* __restrict__ S,
    const float* __restrict__ PE, const float* __restrict__ BUF,
    double* __restrict__ part, int G, int NB)
{
    __shared__ float lds[7168];   // 256 groups * 28 floats = 28 KB

    const int tid = threadIdx.x;
    const int wid = tid >> 6;
    const int g0  = blockIdx.x * 256;
    const int g   = g0 + tid;
    const bool full = (g0 + 256 <= G);   // block-uniform

    float4 tv[7], sv[7];
    bool have = false;

    if (full) {
        const float* gT = T + (size_t)g0 * 28;
        const float* gS = S + (size_t)g0 * 28;

        #pragma unroll
        for (int k = 0; k < 7; ++k) {
            const int fidx = k * 256 + tid;            // per-lane float4 index in chunk
            const int uoff = (k * 256 + wid * 64) * 4; // wave-uniform LDS float offset
            __builtin_amdgcn_global_load_lds((gptr_t)(gT + (size_t)fidx * 4),
                                             (lptr_t)&lds[uoff], 16, 0, 0);
        }
        __syncthreads();   // vmcnt drained before barrier
        {
            const float4* Tl = reinterpret_cast<const float4*>(&lds[tid * 28]);
            #pragma unroll
            for (int d = 0; d < 7; ++d) tv[d] = Tl[d];
        }
        __syncthreads();   // all reads done before overwrite

        #pragma unroll
        for (int k = 0; k < 7; ++k) {
            const int fidx = k * 256 + tid;
            const int uoff = (k * 256 + wid * 64) * 4;
            __builtin_amdgcn_global_load_lds((gptr_t)(gS + (size_t)fidx * 4),
                                             (lptr_t)&lds[uoff], 16, 0, 0);
        }
        __syncthreads();
        {
            const float4* Sl = reinterpret_cast<const float4*>(&lds[tid * 28]);
            #pragma unroll
            for (int d = 0; d < 7; ++d) sv[d] = Sl[d];
        }
        have = true;
    } else if (g < G) {
        const float4* Tp = reinterpret_cast<const float4*>(T) + (size_t)g * 7;
        const float4* Sp = reinterpret_cast<const float4*>(S) + (size_t)g * 7;
        #pragma unroll
        for (int d = 0; d < 7; ++d) { tv[d] = Tp[d]; sv[d] = Sp[d]; }
        have = true;
    }

    double lat = 0.0, en = 0.0, mis = 0.0;

    if (have) {
        const float pe = PE[0];
        const float sq = sqrtf(pe);
        const float b0 = BUF[0], b1 = BUF[1], b2 = BUF[2];

        float fpI[3] = {1.f,1.f,1.f}, fpW[3] = {1.f,1.f,1.f}, fpO[3] = {1.f,1.f,1.f};
        float otI[3] = {1.f,1.f,1.f}, otW[3] = {1.f,1.f,1.f}, otO[3] = {1.f,1.f,1.f};
        float ruI[3] = {1.f,1.f,1.f}, ruW[3] = {1.f,1.f,1.f}, ruO[3] = {1.f,1.f,1.f};
        float macs = 1.f;

        constexpr unsigned IN_D = 0x1D, WT_D = 0x66, OU_D = 0x1B;
        constexpr unsigned IN_R = 0x02, WT_R = 0x19, OU_R = 0x64;

        #pragma unroll
        for (int d = 0; d < 7; ++d) {
            const float4 t = tv[d];
            const float4 s = sv[d];

            const float ct0 = t.x;
            const float ct1 = ct0 * t.y;
            const float ct2 = ct1 * t.z;
            const float u0 = t.x * s.x, u1 = t.y * s.y, u2 = t.z * s.z, u3 = t.w * s.w;
            const float cs0 = u0;
            const float cs1 = cs0 * u1;
            const float cs2 = cs1 * u2;
            const float cs3 = cs2 * u3;
            const float st3 = t.w;
            const float st2 = t.z * st3;
            const float st1 = t.y * st2;

            macs *= cs3;

            if ((IN_D >> d) & 1) {
                fpI[0] *= cs0; fpI[1] *= cs1; fpI[2] *= cs2;
                otI[0] *= st1; otI[1] *= st2; otI[2] *= st3;
            }
            if ((WT_D >> d) & 1) {
                fpW[0] *= cs0; fpW[1] *= cs1; fpW[2] *= cs2;
                otW[0] *= st1; otW[1] *= st2; otW[2] *= st3;
            }
            if ((OU_D >> d) & 1) {
                fpO[0] *= cs0; fpO[1] *= cs1; fpO[2] *= cs2;
                otO[0] *= st1; otO[1] *= st2; otO[2] *= st3;
            }
            if ((IN_R >> d) & 1) { ruI[0] *= ct0; ruI[1] *= ct1; ruI[2] *= ct2; }
            if ((WT_R >> d) & 1) { ruW[0] *= ct0; ruW[1] *= ct1; ruW[2] *= ct2; }
            if ((OU_R >> d) & 1) { ruO[0] *= ct0; ruO[1] *= ct1; ruO[2] *= ct2; }
        }

        const float acc0 = 4.f * ( fpI[2] * otI[2] / (ruI[2] + 1e-9f)
                                 + fpW[2] * otW[2] / (ruW[2] + 1e-9f)
                                 + fpO[2] * otO[2] / (ruO[2] + 1e-9f) );
        const float acc1 = 4.f * ( fpI[1] * otI[1] / (ruI[1] + 1e-9f)
                                 + fpW[1] * otW[1] / (ruW[1] + 1e-9f)
                                 + fpO[1] * otO[1] / (ruO[1] + 1e-9f) );
        const float acc2 = 4.f * ( fpI[0] * otI[0] / (ruI[0] + 1e-9f)
                                 + fpW[0] * otW[0] / (ruW[0] + 1e-9f)
                                 + fpO[0] * otO[0] / (ruO[0] + 1e-9f) );

        const float bw_dram   = 100.0f * 1e9f + 1e-9f;
        const float bw_onchip = sq * 8e9f + 1e-9f;   // 2*sq*4B*1000MHz in B/s
        const float ml = fmaxf(acc0 / bw_dram,
                               fmaxf(acc1, acc2) / bw_onchip);
        const float cl = macs / (pe * 1e9f + 1e-9f);
        lat = (double)fmaxf(cl, ml);

        const float epa0 = 1.2f  + 0.002f * b2;
        const float epa1 = 0.52f + 0.01f  * (b1 / sq);
        const float epa2 = 0.18f;
        en = (double)(macs * 0.56f + (acc0 * epa0 + acc1 * epa1 + acc2 * epa2) * 0.25f);

        const float c = 4.f / 1024.f;
        const float r0 = (fpI[0] + fpW[0] + fpO[0]) * c;
        const float r1 = (fpI[1] + fpW[1] + fpO[1]) * c;
        const float r2 = (fpI[2] + fpW[2] + fpO[2]) * c;
        const float d0 = fmaxf(r0 - b0, 0.f);
        const float d1 = fmaxf(r1 - b1, 0.f);
        const float d2 = fmaxf(r2 - b2, 0.f);
        mis = (double)d0 * d0 + (double)d1 * d1 + (double)d2 * d2;
    }

    // wave (64-lane) shuffle reduction
    #pragma unroll
    for (int off = 32; off > 0; off >>= 1) {
        lat += __shfl_down(lat, off);
        en  += __shfl_down(en,  off);
        mis += __shfl_down(mis, off);
    }

    __shared__ double sred[3][4];
    const int lane = tid & 63;
    if (lane == 0) { sred[0][wid] = lat; sred[1][wid] = en; sred[2][wid] = mis; }
    __syncthreads();

    if (tid == 0) {
        double L = 0.0, E = 0.0, M = 0.0;
        #pragma unroll
        for (int w = 0; w < 4; ++w) { L += sred[0][w]; E += sred[1][w]; M += sred[2][w]; }
        // private per-block slots, plane-major for coalesced final reads; NO atomics.
        part[0 * NB + blockIdx.x] = L;
        part[1 * NB + blockIdx.x] = E;
        part[2 * NB + blockIdx.x] = M;
    }
}

__global__ __launch_bounds__(256) void hpm_final(
    const double* __restrict__ part, int NB,
    const float* __restrict__ PE, const float* __restrict__ BUF,
    float* __restrict__ out)
{
    const int tid = threadIdx.x;
    double L = 0.0, E = 0.0, M = 0.0;
    for (int i = tid; i < NB; i += 256) {
        L += part[0 * NB + i];
        E += part[1 * NB + i];
        M += part[2 * NB + i];
    }

    #pragma unroll
    for (int off = 32; off > 0; off >>= 1) {
        L += __shfl_down(L, off);
        E += __shfl_down(E, off);
        M += __shfl_down(M, off);
    }

    __shared__ double sred[3][4];
    const int wid  = tid >> 6;
    const int lane = tid & 63;
    if (lane == 0) { sred[0][wid] = L; sred[1][wid] = E; sred[2][wid] = M; }
    __syncthreads();

    if (tid == 0) {
        double Lt = 0.0, Et = 0.0, Mt = 0.0;
        #pragma unroll
        for (int w = 0; w < 4; ++w) { Lt += sred[0][w]; Et += sred[1][w]; Mt += sred[2][w]; }
        out[0] = (float)Lt;                                           // total_latency
        out[1] = (float)Et;                                           // total_energy
        out[2] = PE[0] * 0.01f + (BUF[0] + BUF[1] + BUF[2]) * 0.005f; // area
        out[3] = (float)Mt;                                           // total_mismatch
    }
}

extern "C" void kernel_launch(void* const* d_in, const int* in_sizes, int n_in,
                              void* d_out, int out_size, void* d_ws, size_t ws_size,
                              hipStream_t stream) {
    const float* T   = (const float*)d_in[0];   // temporal_factors [G,7,4]
    const float* S   = (const float*)d_in[1];   // spatial_factors  [G,7,4]
    const float* PE  = (const float*)d_in[2];   // num_pes [1]
    const float* BUF = (const float*)d_in[3];   // buffer_sizes_kb [3]
    float* out = (float*)d_out;
    double* ws = (double*)d_ws;

    const int G  = in_sizes[0] / 28;
    const int NB = (G + 255) / 256;

    hipLaunchKernelGGL(hpm_main, dim3(NB), dim3(256), 0, stream,
                       T, S, PE, BUF, ws, G, NB);
    hipLaunchKernelGGL(hpm_final, dim3(1), dim3(256), 0, stream,
                       ws, NB, PE, BUF, out);
}

// Round 6
// 26.522 us; speedup vs baseline: 5.3418x; 1.0571x over previous
//
#include <hip/hip_runtime.h>
#include <hip/hip_bf16.h>

// Dim indices: N=0, K=1, C=2, P=3, Q=4, R=5, S=6
// DIM_MASK rows  -> Input{N,C,P,Q}=0x1D  Weight{K,C,R,S}=0x66  Output{N,K,P,Q}=0x1B
// REUSE_MASK rows-> Input{K}=0x02        Weight{N,P,Q}=0x19    Output{C,R,S}=0x64

typedef const __attribute__((address_space(1))) void* gptr_t;
typedef __attribute__((address_space(3))) void* lptr_t;

#define BLK 256
#define NBK 512   // persistent grid: 2 blocks/CU x 256 CU (LDS 57.4KB/block)

__global__ __launch_bounds__(BLK) void hpm_main(
    const float* __restrict__ T, const float* __restrict__ S,
    const float* __restrict__ PE, const float* __restrict__ BUF,
    double* __restrict__ part, int G)
{
    __shared__ float ldsT[BLK * 28];   // 28 KB
    __shared__ float ldsS[BLK * 28];   // 28 KB

    const int tid = threadIdx.x;
    const int wid = tid >> 6;
    const int NT  = (G + BLK - 1) / BLK;

    // block-uniform scalars
    const float pe = PE[0];
    const float sq = sqrtf(pe);
    const float b0 = BUF[0], b1 = BUF[1], b2 = BUF[2];
    const float bw_dram   = 100.0f * 1e9f + 1e-9f;
    const float bw_onchip = sq * 8e9f + 1e-9f;   // 2*sq*4B*1000MHz in B/s
    const float epa0 = 1.2f  + 0.002f * b2;
    const float epa1 = 0.52f + 0.01f  * (b1 / sq);
    const float epa2 = 0.18f;
    const float inv_pe = 1.0f / (pe * 1e9f + 1e-9f);

    auto issue_dma = [&](int t) {
        const float* gT = T + (size_t)t * BLK * 28;
        const float* gS = S + (size_t)t * BLK * 28;
        #pragma unroll
        for (int k = 0; k < 7; ++k) {
            const int fidx = k * BLK + tid;            // per-lane float4 index in tile
            const int uoff = (k * BLK + wid * 64) * 4; // wave-uniform LDS float offset
            __builtin_amdgcn_global_load_lds((gptr_t)(gT + (size_t)fidx * 4),
                                             (lptr_t)&ldsT[uoff], 16, 0, 0);
            __builtin_amdgcn_global_load_lds((gptr_t)(gS + (size_t)fidx * 4),
                                             (lptr_t)&ldsS[uoff], 16, 0, 0);
        }
    };

    double latA = 0.0, enA = 0.0, misA = 0.0;

    // prologue: prefetch first tile
    {
        const int t0 = blockIdx.x;
        if (t0 < NT && t0 * BLK + BLK <= G) issue_dma(t0);
    }

    for (int t = blockIdx.x; t < NT; t += NBK) {
        const bool full = (t * BLK + BLK <= G);   // block-uniform
        const int  g    = t * BLK + tid;

        float4 tv[7], sv[7];
        bool have = false;

        __syncthreads();   // (a) DMA(t) complete: compiler drains vmcnt before s_barrier

        if (full) {
            const float4* Tl = reinterpret_cast<const float4*>(&ldsT[tid * 28]);
            const float4* Sl = reinterpret_cast<const float4*>(&ldsS[tid * 28]);
            #pragma unroll
            for (int d = 0; d < 7; ++d) { tv[d] = Tl[d]; sv[d] = Sl[d]; }
            have = true;
        } else if (g < G) {
            const float4* Tp = reinterpret_cast<const float4*>(T) + (size_t)g * 7;
            const float4* Sp = reinterpret_cast<const float4*>(S) + (size_t)g * 7;
            #pragma unroll
            for (int d = 0; d < 7; ++d) { tv[d] = Tp[d]; sv[d] = Sp[d]; }
            have = true;
        }

        __syncthreads();   // (b) all lanes done reading LDS before overwriting

        // prefetch next tile (overlaps with compute below)
        {
            const int tn = t + NBK;
            if (tn < NT && tn * BLK + BLK <= G) issue_dma(tn);
        }

        if (have) {
            float fpI[3] = {1.f,1.f,1.f}, fpW[3] = {1.f,1.f,1.f}, fpO[3] = {1.f,1.f,1.f};
            float otI[3] = {1.f,1.f,1.f}, otW[3] = {1.f,1.f,1.f}, otO[3] = {1.f,1.f,1.f};
            float ruI[3] = {1.f,1.f,1.f}, ruW[3] = {1.f,1.f,1.f}, ruO[3] = {1.f,1.f,1.f};
            float macs = 1.f;

            constexpr unsigned IN_D = 0x1D, WT_D = 0x66, OU_D = 0x1B;
            constexpr unsigned IN_R = 0x02, WT_R = 0x19, OU_R = 0x64;

            #pragma unroll
            for (int d = 0; d < 7; ++d) {
                const float4 tt = tv[d];
                const float4 ss = sv[d];

                const float ct0 = tt.x;
                const float ct1 = ct0 * tt.y;
                const float ct2 = ct1 * tt.z;
                const float u0 = tt.x * ss.x, u1 = tt.y * ss.y;
                const float u2 = tt.z * ss.z, u3 = tt.w * ss.w;
                const float cs0 = u0;
                const float cs1 = cs0 * u1;
                const float cs2 = cs1 * u2;
                const float cs3 = cs2 * u3;
                const float st3 = tt.w;
                const float st2 = tt.z * st3;
                const float st1 = tt.y * st2;

                macs *= cs3;

                if ((IN_D >> d) & 1) {
                    fpI[0] *= cs0; fpI[1] *= cs1; fpI[2] *= cs2;
                    otI[0] *= st1; otI[1] *= st2; otI[2] *= st3;
                }
                if ((WT_D >> d) & 1) {
                    fpW[0] *= cs0; fpW[1] *= cs1; fpW[2] *= cs2;
                    otW[0] *= st1; otW[1] *= st2; otW[2] *= st3;
                }
                if ((OU_D >> d) & 1) {
                    fpO[0] *= cs0; fpO[1] *= cs1; fpO[2] *= cs2;
                    otO[0] *= st1; otO[1] *= st2; otO[2] *= st3;
                }
                if ((IN_R >> d) & 1) { ruI[0] *= ct0; ruI[1] *= ct1; ruI[2] *= ct2; }
                if ((WT_R >> d) & 1) { ruW[0] *= ct0; ruW[1] *= ct1; ruW[2] *= ct2; }
                if ((OU_R >> d) & 1) { ruO[0] *= ct0; ruO[1] *= ct1; ruO[2] *= ct2; }
            }

            const float acc0 = 4.f * ( fpI[2] * otI[2] / (ruI[2] + 1e-9f)
                                     + fpW[2] * otW[2] / (ruW[2] + 1e-9f)
                                     + fpO[2] * otO[2] / (ruO[2] + 1e-9f) );
            const float acc1 = 4.f * ( fpI[1] * otI[1] / (ruI[1] + 1e-9f)
                                     + fpW[1] * otW[1] / (ruW[1] + 1e-9f)
                                     + fpO[1] * otO[1] / (ruO[1] + 1e-9f) );
            const float acc2 = 4.f * ( fpI[0] * otI[0] / (ruI[0] + 1e-9f)
                                     + fpW[0] * otW[0] / (ruW[0] + 1e-9f)
                                     + fpO[0] * otO[0] / (ruO[0] + 1e-9f) );

            const float ml = fmaxf(acc0 / bw_dram, fmaxf(acc1, acc2) / bw_onchip);
            const float cl = macs * inv_pe;
            latA += (double)fmaxf(cl, ml);

            enA += (double)(macs * 0.56f + (acc0 * epa0 + acc1 * epa1 + acc2 * epa2) * 0.25f);

            const float c = 4.f / 1024.f;
            const float r0 = (fpI[0] + fpW[0] + fpO[0]) * c;
            const float r1 = (fpI[1] + fpW[1] + fpO[1]) * c;
            const float r2 = (fpI[2] + fpW[2] + fpO[2]) * c;
            const float d0 = fmaxf(r0 - b0, 0.f);
            const float d1 = fmaxf(r1 - b1, 0.f);
            const float d2 = fmaxf(r2 - b2, 0.f);
            misA += (double)d0 * d0 + (double)d1 * d1 + (double)d2 * d2;
        }
    }

    // wave (64-lane) shuffle reduction
    #pragma unroll
    for (int off = 32; off > 0; off >>= 1) {
        latA += __shfl_down(latA, off);
        enA  += __shfl_down(enA,  off);
        misA += __shfl_down(misA, off);
    }

    __shared__ double sred[3][4];
    const int lane = tid & 63;
    if (lane == 0) { sred[0][wid] = latA; sred[1][wid] = enA; sred[2][wid] = misA; }
    __syncthreads();

    if (tid == 0) {
        double L = 0.0, E = 0.0, M = 0.0;
        #pragma unroll
        for (int w = 0; w < 4; ++w) { L += sred[0][w]; E += sred[1][w]; M += sred[2][w]; }
        // private per-block slots, plane-major; NO atomics, NO fences.
        part[0 * NBK + blockIdx.x] = L;
        part[1 * NBK + blockIdx.x] = E;
        part[2 * NBK + blockIdx.x] = M;
    }
}

__global__ __launch_bounds__(256) void hpm_final(
    const double* __restrict__ part,
    const float* __restrict__ PE, const float* __restrict__ BUF,
    float* __restrict__ out)
{
    const int tid = threadIdx.x;
    double L = 0.0, E = 0.0, M = 0.0;
    #pragma unroll
    for (int i = tid; i < NBK; i += 256) {
        L += part[0 * NBK + i];
        E += part[1 * NBK + i];
        M += part[2 * NBK + i];
    }

    #pragma unroll
    for (int off = 32; off > 0; off >>= 1) {
        L += __shfl_down(L, off);
        E += __shfl_down(E, off);
        M += __shfl_down(M, off);
    }

    __shared__ double sred[3][4];
    const int wid  = tid >> 6;
    const int lane = tid & 63;
    if (lane == 0) { sred[0][wid] = L; sred[1][wid] = E; sred[2][wid] = M; }
    __syncthreads();

    if (tid == 0) {
        double Lt = 0.0, Et = 0.0, Mt = 0.0;
        #pragma unroll
        for (int w = 0; w < 4; ++w) { Lt += sred[0][w]; Et += sred[1][w]; Mt += sred[2][w]; }
        out[0] = (float)Lt;                                           // total_latency
        out[1] = (float)Et;                                           // total_energy
        out[2] = PE[0] * 0.01f + (BUF[0] + BUF[1] + BUF[2]) * 0.005f; // area
        out[3] = (float)Mt;                                           // total_mismatch
    }
}

extern "C" void kernel_launch(void* const* d_in, const int* in_sizes, int n_in,
                              void* d_out, int out_size, void* d_ws, size_t ws_size,
                              hipStream_t stream) {
    const float* T   = (const float*)d_in[0];   // temporal_factors [G,7,4]
    const float* S   = (const float*)d_in[1];   // spatial_factors  [G,7,4]
    const float* PE  = (const float*)d_in[2];   // num_pes [1]
    const float* BUF = (const float*)d_in[3];   // buffer_sizes_kb [3]
    float* out = (float*)d_out;
    double* ws = (double*)d_ws;

    const int G = in_sizes[0] / 28;

    hipLaunchKernelGGL(hpm_main, dim3(NBK), dim3(BLK), 0, stream,
                       T, S, PE, BUF, ws, G);
    hipLaunchKernelGGL(hpm_final, dim3(1), dim3(256), 0, stream,
                       ws, PE, BUF, out);
}

// Round 7
// 26.251 us; speedup vs baseline: 5.3969x; 1.0103x over previous
//
#include <hip/hip_runtime.h>
#include <hip/hip_bf16.h>

// Dim indices: N=0, K=1, C=2, P=3, Q=4, R=5, S=6
// DIM_MASK rows  -> Input{N,C,P,Q}=0x1D  Weight{K,C,R,S}=0x66  Output{N,K,P,Q}=0x1B
// REUSE_MASK rows-> Input{K}=0x02        Weight{N,P,Q}=0x19    Output{C,R,S}=0x64

typedef const __attribute__((address_space(1))) void* gptr_t;
typedef __attribute__((address_space(3))) void* lptr_t;

#define BLK 256
#define NBK 256   // persistent: 1 block/CU, LDS 112 KB, 2-deep DMA pipeline

__global__ __launch_bounds__(BLK) void hpm_main(
    const float* __restrict__ T, const float* __restrict__ S,
    const float* __restrict__ PE, const float* __restrict__ BUF,
    double* __restrict__ part, int G)
{
    __shared__ float ldsT[2][BLK * 28];   // 2 x 28 KB
    __shared__ float ldsS[2][BLK * 28];   // 2 x 28 KB

    const int tid = threadIdx.x;
    const int wid = tid >> 6;
    const int NTF = G / BLK;              // full tiles only in the pipeline
    const int b   = blockIdx.x;
    const int cnt = (NTF > b) ? ((NTF - 1 - b) / NBK + 1) : 0;

    // block-uniform scalars (s_load, complete long before the pipeline matters)
    const float pe = PE[0];
    const float sq = sqrtf(pe);
    const float b0 = BUF[0], b1 = BUF[1], b2 = BUF[2];
    const float bw_dram   = 100.0f * 1e9f + 1e-9f;
    const float bw_onchip = sq * 8e9f + 1e-9f;   // 2*sq*4B*1000MHz in B/s
    const float epa0 = 1.2f  + 0.002f * b2;
    const float epa1 = 0.52f + 0.01f  * (b1 / sq);
    const float epa2 = 0.18f;
    const float inv_pe = 1.0f / (pe * 1e9f + 1e-9f);

    constexpr unsigned IN_D = 0x1D, WT_D = 0x66, OU_D = 0x1B;
    constexpr unsigned IN_R = 0x02, WT_R = 0x19, OU_R = 0x64;

    auto issue = [&](int t, int buf) {   // 14 global_load_lds per thread
        const float* gT = T + (size_t)t * BLK * 28;
        const float* gS = S + (size_t)t * BLK * 28;
        #pragma unroll
        for (int k = 0; k < 7; ++k) {
            const int fidx = k * BLK + tid;            // per-lane float4 index in tile
            const int uoff = (k * BLK + wid * 64) * 4; // wave-uniform LDS float offset
            __builtin_amdgcn_global_load_lds((gptr_t)(gT + (size_t)fidx * 4),
                                             (lptr_t)&ldsT[buf][uoff], 16, 0, 0);
            __builtin_amdgcn_global_load_lds((gptr_t)(gS + (size_t)fidx * 4),
                                             (lptr_t)&ldsS[buf][uoff], 16, 0, 0);
        }
    };

    double latA = 0.0, enA = 0.0, misA = 0.0;

    auto accumulate = [&](const float4* tv, const float4* sv) {
        float fpI[3] = {1.f,1.f,1.f}, fpW[3] = {1.f,1.f,1.f}, fpO[3] = {1.f,1.f,1.f};
        float otI[3] = {1.f,1.f,1.f}, otW[3] = {1.f,1.f,1.f}, otO[3] = {1.f,1.f,1.f};
        float ruI[3] = {1.f,1.f,1.f}, ruW[3] = {1.f,1.f,1.f}, ruO[3] = {1.f,1.f,1.f};
        float macs = 1.f;

        #pragma unroll
        for (int d = 0; d < 7; ++d) {
            const float4 tt = tv[d];
            const float4 ss = sv[d];

            const float ct0 = tt.x;
            const float ct1 = ct0 * tt.y;
            const float ct2 = ct1 * tt.z;
            const float u0 = tt.x * ss.x, u1 = tt.y * ss.y;
            const float u2 = tt.z * ss.z, u3 = tt.w * ss.w;
            const float cs0 = u0;
            const float cs1 = cs0 * u1;
            const float cs2 = cs1 * u2;
            const float cs3 = cs2 * u3;
            const float st3 = tt.w;
            const float st2 = tt.z * st3;
            const float st1 = tt.y * st2;

            macs *= cs3;

            if ((IN_D >> d) & 1) {
                fpI[0] *= cs0; fpI[1] *= cs1; fpI[2] *= cs2;
                otI[0] *= st1; otI[1] *= st2; otI[2] *= st3;
            }
            if ((WT_D >> d) & 1) {
                fpW[0] *= cs0; fpW[1] *= cs1; fpW[2] *= cs2;
                otW[0] *= st1; otW[1] *= st2; otW[2] *= st3;
            }
            if ((OU_D >> d) & 1) {
                fpO[0] *= cs0; fpO[1] *= cs1; fpO[2] *= cs2;
                otO[0] *= st1; otO[1] *= st2; otO[2] *= st3;
            }
            if ((IN_R >> d) & 1) { ruI[0] *= ct0; ruI[1] *= ct1; ruI[2] *= ct2; }
            if ((WT_R >> d) & 1) { ruW[0] *= ct0; ruW[1] *= ct1; ruW[2] *= ct2; }
            if ((OU_R >> d) & 1) { ruO[0] *= ct0; ruO[1] *= ct1; ruO[2] *= ct2; }
        }

        const float acc0 = 4.f * ( fpI[2] * otI[2] / (ruI[2] + 1e-9f)
                                 + fpW[2] * otW[2] / (ruW[2] + 1e-9f)
                                 + fpO[2] * otO[2] / (ruO[2] + 1e-9f) );
        const float acc1 = 4.f * ( fpI[1] * otI[1] / (ruI[1] + 1e-9f)
                                 + fpW[1] * otW[1] / (ruW[1] + 1e-9f)
                                 + fpO[1] * otO[1] / (ruO[1] + 1e-9f) );
        const float acc2 = 4.f * ( fpI[0] * otI[0] / (ruI[0] + 1e-9f)
                                 + fpW[0] * otW[0] / (ruW[0] + 1e-9f)
                                 + fpO[0] * otO[0] / (ruO[0] + 1e-9f) );

        const float ml = fmaxf(acc0 / bw_dram, fmaxf(acc1, acc2) / bw_onchip);
        const float cl = macs * inv_pe;
        latA += (double)fmaxf(cl, ml);

        enA += (double)(macs * 0.56f + (acc0 * epa0 + acc1 * epa1 + acc2 * epa2) * 0.25f);

        const float c = 4.f / 1024.f;
        const float r0 = (fpI[0] + fpW[0] + fpO[0]) * c;
        const float r1 = (fpI[1] + fpW[1] + fpO[1]) * c;
        const float r2 = (fpI[2] + fpW[2] + fpO[2]) * c;
        const float d0 = fmaxf(r0 - b0, 0.f);
        const float d1 = fmaxf(r1 - b1, 0.f);
        const float d2 = fmaxf(r2 - b2, 0.f);
        misA += (double)d0 * d0 + (double)d1 * d1 + (double)d2 * d2;
    };

    // ---- 2-deep pipeline prologue ----
    if (cnt > 0) issue(b, 0);
    if (cnt > 1) issue(b + NBK, 1);

    for (int i = 0; i < cnt; ++i) {
        // wait for tile i's 14 loads; keep tile i+1's (if any) in flight
        if (i + 1 < cnt) { asm volatile("s_waitcnt vmcnt(14)" ::: "memory"); }
        else             { asm volatile("s_waitcnt vmcnt(0)"  ::: "memory"); }
        __builtin_amdgcn_sched_barrier(0);
        __builtin_amdgcn_s_barrier();           // (A) buffer i ready for all waves
        __builtin_amdgcn_sched_barrier(0);

        const int buf = i & 1;
        float4 tv[7], sv[7];
        {
            const float4* Tl = reinterpret_cast<const float4*>(&ldsT[buf][tid * 28]);
            const float4* Sl = reinterpret_cast<const float4*>(&ldsS[buf][tid * 28]);
            #pragma unroll
            for (int d = 0; d < 7; ++d) { tv[d] = Tl[d]; sv[d] = Sl[d]; }
        }
        asm volatile("s_waitcnt lgkmcnt(0)" ::: "memory");
        __builtin_amdgcn_sched_barrier(0);      // rule #18: pin ops after the wait
        __builtin_amdgcn_s_barrier();           // (B) all waves done reading buffer
        __builtin_amdgcn_sched_barrier(0);

        if (i + 2 < cnt) issue(b + (size_t)(i + 2) * NBK, buf);  // refill freed buffer

        accumulate(tv, sv);
    }

    // ---- tail: partial tile (block 0 only), vmcnt fully drained above ----
    if (b == 0) {
        const int g = NTF * BLK + tid;
        if (g < G) {
            float4 tv[7], sv[7];
            const float4* Tp = reinterpret_cast<const float4*>(T) + (size_t)g * 7;
            const float4* Sp = reinterpret_cast<const float4*>(S) + (size_t)g * 7;
            #pragma unroll
            for (int d = 0; d < 7; ++d) { tv[d] = Tp[d]; sv[d] = Sp[d]; }
            accumulate(tv, sv);
        }
    }

    // ---- wave (64-lane) shuffle reduction ----
    #pragma unroll
    for (int off = 32; off > 0; off >>= 1) {
        latA += __shfl_down(latA, off);
        enA  += __shfl_down(enA,  off);
        misA += __shfl_down(misA, off);
    }

    __shared__ double sred[3][4];
    const int lane = tid & 63;
    if (lane == 0) { sred[0][wid] = latA; sred[1][wid] = enA; sred[2][wid] = misA; }
    __syncthreads();

    if (tid == 0) {
        double L = 0.0, E = 0.0, M = 0.0;
        #pragma unroll
        for (int w = 0; w < 4; ++w) { L += sred[0][w]; E += sred[1][w]; M += sred[2][w]; }
        // private per-block slots, plane-major; NO atomics, NO fences.
        part[0 * NBK + blockIdx.x] = L;
        part[1 * NBK + blockIdx.x] = E;
        part[2 * NBK + blockIdx.x] = M;
    }
}

__global__ __launch_bounds__(256) void hpm_final(
    const double* __restrict__ part,
    const float* __restrict__ PE, const float* __restrict__ BUF,
    float* __restrict__ out)
{
    const int tid = threadIdx.x;
    double L = 0.0, E = 0.0, M = 0.0;
    if (tid < NBK) {
        L = part[0 * NBK + tid];
        E = part[1 * NBK + tid];
        M = part[2 * NBK + tid];
    }

    #pragma unroll
    for (int off = 32; off > 0; off >>= 1) {
        L += __shfl_down(L, off);
        E += __shfl_down(E, off);
        M += __shfl_down(M, off);
    }

    __shared__ double sred[3][4];
    const int wid  = tid >> 6;
    const int lane = tid & 63;
    if (lane == 0) { sred[0][wid] = L; sred[1][wid] = E; sred[2][wid] = M; }
    __syncthreads();

    if (tid == 0) {
        double Lt = 0.0, Et = 0.0, Mt = 0.0;
        #pragma unroll
        for (int w = 0; w < 4; ++w) { Lt += sred[0][w]; Et += sred[1][w]; Mt += sred[2][w]; }
        out[0] = (float)Lt;                                           // total_latency
        out[1] = (float)Et;                                           // total_energy
        out[2] = PE[0] * 0.01f + (BUF[0] + BUF[1] + BUF[2]) * 0.005f; // area
        out[3] = (float)Mt;                                           // total_mismatch
    }
}

extern "C" void kernel_launch(void* const* d_in, const int* in_sizes, int n_in,
                              void* d_out, int out_size, void* d_ws, size_t ws_size,
                              hipStream_t stream) {
    const float* T   = (const float*)d_in[0];   // temporal_factors [G,7,4]
    const float* S   = (const float*)d_in[1];   // spatial_factors  [G,7,4]
    const float* PE  = (const float*)d_in[2];   // num_pes [1]
    const float* BUF = (const float*)d_in[3];   // buffer_sizes_kb [3]
    float* out = (float*)d_out;
    double* ws = (double*)d_ws;

    const int G = in_sizes[0] / 28;

    hipLaunchKernelGGL(hpm_main, dim3(NBK), dim3(BLK), 0, stream,
                       T, S, PE, BUF, ws, G);
    hipLaunchKernelGGL(hpm_final, dim3(1), dim3(256), 0, stream,
                       ws, PE, BUF, out);
}

// Round 8
// 26.033 us; speedup vs baseline: 5.4421x; 1.0084x over previous
//
#include <hip/hip_runtime.h>
#include <hip/hip_bf16.h>

// Dim indices: N=0, K=1, C=2, P=3, Q=4, R=5, S=6
// DIM_MASK rows  -> Input{N,C,P,Q}=0x1D  Weight{K,C,R,S}=0x66  Output{N,K,P,Q}=0x1B
// REUSE_MASK rows-> Input{K}=0x02        Weight{N,P,Q}=0x19    Output{C,R,S}=0x64

typedef const __attribute__((address_space(1))) void* gptr_t;
typedef __attribute__((address_space(3))) void* lptr_t;

#define BLK   256
#define NBK   256                 // persistent: 1 block/CU
#define WPB   4                   // waves per block
#define NWAVE (NBK * WPB)         // 1024 self-paced wave streams
#define TGRP  64                  // groups per wave-tile (= 1 lane per group)

__device__ __forceinline__ float fast_rcp(float x) {
    float r;
    asm("v_rcp_f32 %0, %1" : "=v"(r) : "v"(x));
    return r;
}

__global__ __launch_bounds__(BLK) void hpm_main(
    const float* __restrict__ T, const float* __restrict__ S,
    const float* __restrict__ PE, const float* __restrict__ BUF,
    double* __restrict__ part, int G)
{
    // per-wave private: [wave][buf][T/S][64 groups * 28 floats] = 4*2*2*7KB = 112 KB
    __shared__ float lds[WPB][2][2][TGRP * 28];

    const int tid  = threadIdx.x;
    const int w    = tid >> 6;
    const int lane = tid & 63;
    const int W    = blockIdx.x * WPB + w;          // global wave id
    const int NT   = G / TGRP;                      // full 64-group tiles
    const int cnt  = (NT > W) ? ((NT - 1 - W) / NWAVE + 1) : 0;

    // block-uniform scalars; drain their loads so they can't perturb vmcnt counting
    const float pe = PE[0];
    const float sq = sqrtf(pe);
    const float b0 = BUF[0], b1 = BUF[1], b2 = BUF[2];
    const float inv_bw_dram   = 1.0f / (100.0f * 1e9f + 1e-9f);
    const float inv_bw_onchip = 1.0f / (sq * 8e9f + 1e-9f);   // 2*sq*4B*1000MHz in B/s
    const float epa0 = 1.2f  + 0.002f * b2;
    const float epa1 = 0.52f + 0.01f  * (b1 / sq);
    const float epa2 = 0.18f;
    const float inv_pe = 1.0f / (pe * 1e9f + 1e-9f);
    asm volatile("s_waitcnt vmcnt(0) lgkmcnt(0)" ::: "memory");

    constexpr unsigned IN_D = 0x1D, WT_D = 0x66, OU_D = 0x1B;
    constexpr unsigned IN_R = 0x02, WT_R = 0x19, OU_R = 0x64;

    auto issue = [&](int t, int buf) {   // 14 VMEM instrs per wave per tile
        const float* gT = T + (size_t)t * (TGRP * 28);
        const float* gS = S + (size_t)t * (TGRP * 28);
        #pragma unroll
        for (int k = 0; k < 7; ++k) {
            const int fo = (k * 64 + lane) * 4;        // per-lane float offset
            __builtin_amdgcn_global_load_lds((gptr_t)(gT + fo),
                                             (lptr_t)&lds[w][buf][0][k * 256], 16, 0, 0);
            __builtin_amdgcn_global_load_lds((gptr_t)(gS + fo),
                                             (lptr_t)&lds[w][buf][1][k * 256], 16, 0, 0);
        }
    };

    double latA = 0.0, enA = 0.0, misA = 0.0;

    auto accumulate = [&](const float4* tv, const float4* sv) {
        float fpI[3] = {1.f,1.f,1.f}, fpW[3] = {1.f,1.f,1.f}, fpO[3] = {1.f,1.f,1.f};
        float otI[3] = {1.f,1.f,1.f}, otW[3] = {1.f,1.f,1.f}, otO[3] = {1.f,1.f,1.f};
        float ruI[3] = {1.f,1.f,1.f}, ruW[3] = {1.f,1.f,1.f}, ruO[3] = {1.f,1.f,1.f};
        float macs = 1.f;

        #pragma unroll
        for (int d = 0; d < 7; ++d) {
            const float4 tt = tv[d];
            const float4 ss = sv[d];

            const float ct0 = tt.x;
            const float ct1 = ct0 * tt.y;
            const float ct2 = ct1 * tt.z;
            const float u0 = tt.x * ss.x, u1 = tt.y * ss.y;
            const float u2 = tt.z * ss.z, u3 = tt.w * ss.w;
            const float cs0 = u0;
            const float cs1 = cs0 * u1;
            const float cs2 = cs1 * u2;
            const float cs3 = cs2 * u3;
            const float st3 = tt.w;
            const float st2 = tt.z * st3;
            const float st1 = tt.y * st2;

            macs *= cs3;

            if ((IN_D >> d) & 1) {
                fpI[0] *= cs0; fpI[1] *= cs1; fpI[2] *= cs2;
                otI[0] *= st1; otI[1] *= st2; otI[2] *= st3;
            }
            if ((WT_D >> d) & 1) {
                fpW[0] *= cs0; fpW[1] *= cs1; fpW[2] *= cs2;
                otW[0] *= st1; otW[1] *= st2; otW[2] *= st3;
            }
            if ((OU_D >> d) & 1) {
                fpO[0] *= cs0; fpO[1] *= cs1; fpO[2] *= cs2;
                otO[0] *= st1; otO[1] *= st2; otO[2] *= st3;
            }
            if ((IN_R >> d) & 1) { ruI[0] *= ct0; ruI[1] *= ct1; ruI[2] *= ct2; }
            if ((WT_R >> d) & 1) { ruW[0] *= ct0; ruW[1] *= ct1; ruW[2] *= ct2; }
            if ((OU_R >> d) & 1) { ruO[0] *= ct0; ruO[1] *= ct1; ruO[2] *= ct2; }
        }

        // v_rcp_f32 (rel err ~1e-7) instead of IEEE divide: 1 instr vs ~10
        const float acc0 = 4.f * ( fpI[2] * otI[2] * fast_rcp(ruI[2] + 1e-9f)
                                 + fpW[2] * otW[2] * fast_rcp(ruW[2] + 1e-9f)
                                 + fpO[2] * otO[2] * fast_rcp(ruO[2] + 1e-9f) );
        const float acc1 = 4.f * ( fpI[1] * otI[1] * fast_rcp(ruI[1] + 1e-9f)
                                 + fpW[1] * otW[1] * fast_rcp(ruW[1] + 1e-9f)
                                 + fpO[1] * otO[1] * fast_rcp(ruO[1] + 1e-9f) );
        const float acc2 = 4.f * ( fpI[0] * otI[0] * fast_rcp(ruI[0] + 1e-9f)
                                 + fpW[0] * otW[0] * fast_rcp(ruW[0] + 1e-9f)
                                 + fpO[0] * otO[0] * fast_rcp(ruO[0] + 1e-9f) );

        const float ml = fmaxf(acc0 * inv_bw_dram, fmaxf(acc1, acc2) * inv_bw_onchip);
        const float cl = macs * inv_pe;
        latA += (double)fmaxf(cl, ml);

        enA += (double)(macs * 0.56f + (acc0 * epa0 + acc1 * epa1 + acc2 * epa2) * 0.25f);

        const float c = 4.f / 1024.f;
        const float r0 = (fpI[0] + fpW[0] + fpO[0]) * c;
        const float r1 = (fpI[1] + fpW[1] + fpO[1]) * c;
        const float r2 = (fpI[2] + fpW[2] + fpO[2]) * c;
        const float d0 = fmaxf(r0 - b0, 0.f);
        const float d1 = fmaxf(r1 - b1, 0.f);
        const float d2 = fmaxf(r2 - b2, 0.f);
        misA += (double)d0 * d0 + (double)d1 * d1 + (double)d2 * d2;
    };

    // ---- 2-deep per-wave pipeline, NO barriers in the hot loop ----
    if (cnt > 0) issue(W, 0);
    if (cnt > 1) issue(W + NWAVE, 1);

    for (int i = 0; i < cnt; ++i) {
        // wait for tile i's 14 loads; keep tile i+1's 14 in flight (per-wave counter)
        if (i + 1 < cnt) asm volatile("s_waitcnt vmcnt(14)" ::: "memory");
        else             asm volatile("s_waitcnt vmcnt(0)"  ::: "memory");

        const int buf = i & 1;
        float4 tv[7], sv[7];
        {
            const float4* Tl = reinterpret_cast<const float4*>(&lds[w][buf][0][lane * 28]);
            const float4* Sl = reinterpret_cast<const float4*>(&lds[w][buf][1][lane * 28]);
            #pragma unroll
            for (int d = 0; d < 7; ++d) { tv[d] = Tl[d]; sv[d] = Sl[d]; }
        }
        // reads must land before DMA overwrites this buffer (no barrier needed: wave-private)
        asm volatile("s_waitcnt lgkmcnt(0)" ::: "memory");
        __builtin_amdgcn_sched_barrier(0);

        if (i + 2 < cnt) issue(W + (i + 2) * NWAVE, buf);

        accumulate(tv, sv);
    }

    // ---- tail: last global wave handles G % 64 groups (vmcnt fully drained) ----
    if (W == NWAVE - 1) {
        const int g = NT * TGRP + lane;
        if (g < G) {
            float4 tv[7], sv[7];
            const float4* Tp = reinterpret_cast<const float4*>(T) + (size_t)g * 7;
            const float4* Sp = reinterpret_cast<const float4*>(S) + (size_t)g * 7;
            #pragma unroll
            for (int d = 0; d < 7; ++d) { tv[d] = Tp[d]; sv[d] = Sp[d]; }
            accumulate(tv, sv);
        }
    }

    // ---- wave (64-lane) shuffle reduction ----
    #pragma unroll
    for (int off = 32; off > 0; off >>= 1) {
        latA += __shfl_down(latA, off);
        enA  += __shfl_down(enA,  off);
        misA += __shfl_down(misA, off);
    }

    __shared__ double sred[3][WPB];
    if (lane == 0) { sred[0][w] = latA; sred[1][w] = enA; sred[2][w] = misA; }
    __syncthreads();

    if (tid == 0) {
        double L = 0.0, E = 0.0, M = 0.0;
        #pragma unroll
        for (int v = 0; v < WPB; ++v) { L += sred[0][v]; E += sred[1][v]; M += sred[2][v]; }
        // private per-block slots, plane-major; NO atomics, NO fences.
        part[0 * NBK + blockIdx.x] = L;
        part[1 * NBK + blockIdx.x] = E;
        part[2 * NBK + blockIdx.x] = M;
    }
}

__global__ __launch_bounds__(256) void hpm_final(
    const double* __restrict__ part,
    const float* __restrict__ PE, const float* __restrict__ BUF,
    float* __restrict__ out)
{
    const int tid = threadIdx.x;
    double L = 0.0, E = 0.0, M = 0.0;
    if (tid < NBK) {
        L = part[0 * NBK + tid];
        E = part[1 * NBK + tid];
        M = part[2 * NBK + tid];
    }

    #pragma unroll
    for (int off = 32; off > 0; off >>= 1) {
        L += __shfl_down(L, off);
        E += __shfl_down(E, off);
        M += __shfl_down(M, off);
    }

    __shared__ double sred[3][4];
    const int wid  = tid >> 6;
    const int lane = tid & 63;
    if (lane == 0) { sred[0][wid] = L; sred[1][wid] = E; sred[2][wid] = M; }
    __syncthreads();

    if (tid == 0) {
        double Lt = 0.0, Et = 0.0, Mt = 0.0;
        #pragma unroll
        for (int v = 0; v < 4; ++v) { Lt += sred[0][v]; Et += sred[1][v]; Mt += sred[2][v]; }
        out[0] = (float)Lt;                                           // total_latency
        out[1] = (float)Et;                                           // total_energy
        out[2] = PE[0] * 0.01f + (BUF[0] + BUF[1] + BUF[2]) * 0.005f; // area
        out[3] = (float)Mt;                                           // total_mismatch
    }
}

extern "C" void kernel_launch(void* const* d_in, const int* in_sizes, int n_in,
                              void* d_out, int out_size, void* d_ws, size_t ws_size,
                              hipStream_t stream) {
    const float* T   = (const float*)d_in[0];   // temporal_factors [G,7,4]
    const float* S   = (const float*)d_in[1];   // spatial_factors  [G,7,4]
    const float* PE  = (const float*)d_in[2];   // num_pes [1]
    const float* BUF = (const float*)d_in[3];   // buffer_sizes_kb [3]
    float* out = (float*)d_out;
    double* ws = (double*)d_ws;

    const int G = in_sizes[0] / 28;

    hipLaunchKernelGGL(hpm_main, dim3(NBK), dim3(BLK), 0, stream,
                       T, S, PE, BUF, ws, G);
    hipLaunchKernelGGL(hpm_final, dim3(1), dim3(256), 0, stream,
                       ws, PE, BUF, out);
}